// Round 3
// baseline (217.605 us; speedup 1.0000x reference)
//
#include <hip/hip_runtime.h>

#define NN 384
#define CC 128
#define NPOS (NN * NN)  // 147456

typedef short bf8_t __attribute__((ext_vector_type(8)));
typedef float f32x4_t __attribute__((ext_vector_type(4)));

#define MFMA16(a, b, c) __builtin_amdgcn_mfma_f32_16x16x32_bf16((a), (b), (c), 0, 0, 0)

__device__ __forceinline__ unsigned short f2bf(float f) {
  unsigned int u = __builtin_bit_cast(unsigned int, f);
  u += 0x7fffu + ((u >> 16) & 1u);  // RNE
  return (unsigned short)(u >> 16);
}
__device__ __forceinline__ float bf2f(unsigned short s) {
  return __builtin_bit_cast(float, ((unsigned int)s) << 16);
}
__device__ __forceinline__ float sigm(float x) { return 1.0f / (1.0f + __expf(-x)); }

// ---------------- kW: fp32 -> bf16 weight concat [768][128] -----------------
// rows 0-127: w1i, 128-255: w1i_s, 256-383: w1j, 384-511: w1j_s, 512-639: w3, 640-767: w2
__global__ __launch_bounds__(256) void kW(const float* __restrict__ a,
                                          const float* __restrict__ b,
                                          const float* __restrict__ c,
                                          const float* __restrict__ d,
                                          const float* __restrict__ e,
                                          const float* __restrict__ f,
                                          unsigned short* __restrict__ o) {
  int idx = (blockIdx.x * 256 + threadIdx.x) * 4;
  const float* s = f;  // compare-chain, not runtime-indexed array (avoids scratch)
  if (idx < 16384) s = a;
  else if (idx < 32768) s = b;
  else if (idx < 49152) s = c;
  else if (idx < 65536) s = d;
  else if (idx < 81920) s = e;
  int off = idx & 16383;
  float4 v = *(const float4*)(s + off);
  o[idx + 0] = f2bf(v.x);
  o[idx + 1] = f2bf(v.y);
  o[idx + 2] = f2bf(v.z);
  o[idx + 3] = f2bf(v.w);
}

// ---------------- kA: LN1 + 5 projections + gates, 10-phase dbuf pipeline ----
// block: 128 positions (row ii, k0..k0+127), 256 threads / 4 waves.
// LDS (50.5KB): wb dbuf 2x16KB (also LN staging), gather 16KB, bias table 2.5KB.
// Weight chunks = 64 rows x 128 cols bf16, staged with counted vmcnt(4) so the
// next chunk's global_load_lds stay in flight across barriers.
__global__ __launch_bounds__(256, 3) void kA(
    const float* __restrict__ x, const float* __restrict__ n1g,
    const float* __restrict__ n1b, const unsigned short* __restrict__ wcat,
    const float* __restrict__ b1i, const float* __restrict__ b1is,
    const float* __restrict__ b1j, const float* __restrict__ b1js,
    const float* __restrict__ b3v, unsigned short* __restrict__ i_s,
    unsigned short* __restrict__ j_s, unsigned short* __restrict__ g3) {
  __shared__ __align__(16) unsigned short lds[25856];
  // [0,8192): buf0   [8192,16384): buf1   (together = LN staging [128][128])
  // [16384,24576): gather tile    [24576,25856): bias table (640 floats)
  unsigned short* gt = lds + 16384;
  float* bl = (float*)(lds + 24576);

  int blk = blockIdx.x;
  int ii = blk / 3;
  int k0 = (blk % 3) * 128;
  int t = threadIdx.x;
  int lane = t & 63, wave = t >> 6;
  int lr = lane & 15, lh = lane >> 4;

  // ---- bias preload: rows m: 0=b1i 1=b1i_s 2=b1j 3=b1j_s 4=b3 ----
  if (t < 160) {
    int m = t >> 5, e4 = t & 31;
    const float* bp = (m == 0) ? b1i : (m == 1) ? b1is : (m == 2) ? b1j : (m == 3) ? b1js : b3v;
    ((float4*)bl)[m * 32 + e4] = ((const float4*)bp)[e4];
  }

  // ---- LN1: 2 threads per position, 64 channels each; XOR-swizzled LDS write --
  {
    int pos = t >> 1, half = t & 1;
    const float* xr = x + (size_t)(ii * NN + k0 + pos) * CC + half * 64;
    float v[64];
    float s = 0.f;
#pragma unroll
    for (int a = 0; a < 16; ++a) {
      float4 f4 = ((const float4*)xr)[a];
      v[4 * a + 0] = f4.x; v[4 * a + 1] = f4.y;
      v[4 * a + 2] = f4.z; v[4 * a + 3] = f4.w;
      s += f4.x + f4.y + f4.z + f4.w;
    }
    s += __shfl_xor(s, 1);
    float mu = s * (1.0f / CC);
    float vs = 0.f;
#pragma unroll
    for (int a = 0; a < 64; ++a) { float d = v[a] - mu; vs += d * d; }
    vs += __shfl_xor(vs, 1);
    float rs = rsqrtf(vs * (1.0f / CC) + 1e-5f);
#pragma unroll
    for (int a8 = 0; a8 < 8; ++a8) {
      union { bf8_t v8; unsigned short e[8]; } u;
#pragma unroll
      for (int e = 0; e < 8; ++e) {
        int c = half * 64 + a8 * 8 + e;
        u.e[e] = f2bf((v[a8 * 8 + e] - mu) * rs * n1g[c] + n1b[c]);
      }
      int slot = (half * 8 + a8) ^ (pos & 7);
      *(bf8_t*)&lds[pos * 128 + slot * 8] = u.v8;
    }
  }
  __syncthreads();

  // ---- X fragments for this wave's 32 positions (swizzled read) ----
  bf8_t xf[2][4];
#pragma unroll
  for (int nt = 0; nt < 2; ++nt)
#pragma unroll
    for (int kk = 0; kk < 4; ++kk) {
      int row = wave * 32 + nt * 16 + lr;
      int slot = (kk * 4 + lh) ^ (row & 7);
      xf[nt][kk] = *(const bf8_t*)&lds[row * 128 + slot * 8];
    }
  __syncthreads();

  // ---- 10-chunk pipeline. chunk k -> 64-row block blk64[k] of wcat ----
  // order: p0V h0, p0G h0, p0V h1, p0G h1, p1V h0, p1G h0, p1V h1, p1G h1, w3 h0, w3 h1
  constexpr int blk64[10] = {0, 2, 1, 3, 4, 6, 5, 7, 8, 9};
  auto ISSUE = [&](int k, int bsel) {
    const unsigned short* base = wcat + (size_t)blk64[k] * 8192;
#pragma unroll
    for (int it = 0; it < 4; ++it) {
      int u = it * 256 + t;
      int row = u >> 4, sl = u & 15;
      int slg = sl ^ (row & 7);  // pre-swizzled global source, linear LDS dest
      __builtin_amdgcn_global_load_lds(
          (const __attribute__((address_space(1))) unsigned int*)(base + row * CC + slg * 8),
          (__attribute__((address_space(3))) unsigned int*)(lds + bsel * 8192 + u * 8), 16, 0, 0);
    }
  };
  auto COMP = [&](f32x4_t (&A)[4][2], const unsigned short* buf) {
#pragma unroll
    for (int ct = 0; ct < 4; ++ct)
#pragma unroll
      for (int kk = 0; kk < 4; ++kk) {
        int rv = ct * 16 + lr;
        int slot = (kk * 4 + lh) ^ (rv & 7);
        bf8_t w = *(const bf8_t*)&buf[rv * 128 + slot * 8];
#pragma unroll
        for (int nt = 0; nt < 2; ++nt) A[ct][nt] = MFMA16(w, xf[nt][kk], A[ct][nt]);
      }
  };

  f32x4_t z4 = {0.f, 0.f, 0.f, 0.f};
  f32x4_t accV[4][2], accG[4][2], acc3[2][4];
  ISSUE(0, 0);
  ISSUE(1, 1);
#pragma unroll 10
  for (int k = 0; k < 10; ++k) {
    if (k < 9) asm volatile("s_waitcnt vmcnt(4)" ::: "memory");
    else       asm volatile("s_waitcnt vmcnt(0)" ::: "memory");
    __builtin_amdgcn_s_barrier();
    __builtin_amdgcn_sched_barrier(0);
    const unsigned short* buf = lds + (k & 1) * 8192;
    if (k < 8) {
      if ((k & 1) == 0) {
#pragma unroll
        for (int ct = 0; ct < 4; ++ct)
#pragma unroll
          for (int nt = 0; nt < 2; ++nt) accV[ct][nt] = z4;
        COMP(accV, buf);
      } else {
#pragma unroll
        for (int ct = 0; ct < 4; ++ct)
#pragma unroll
          for (int nt = 0; nt < 2; ++nt) accG[ct][nt] = z4;
        COMP(accG, buf);
        // epilogue: gate + gather + cooperative 256B-contiguous stores
        int pair = k >> 2, h = (k >> 1) & 1;
#pragma unroll
        for (int ct = 0; ct < 4; ++ct)
#pragma unroll
          for (int nt = 0; nt < 2; ++nt)
#pragma unroll
            for (int r = 0; r < 4; ++r) {
              int cl = ct * 16 + lh * 4 + r;
              int c = h * 64 + cl;
              float val = accV[ct][nt][r] + bl[pair * 256 + c];
              float gat = accG[ct][nt][r] + bl[pair * 256 + 128 + c];
              int pos = wave * 32 + nt * 16 + lr;
              int sw = ((ct * 4 + lh) & 7) << 4;
              gt[cl * 128 + (pos ^ sw)] = f2bf(val * sigm(gat));
            }
        asm volatile("s_waitcnt lgkmcnt(0)" ::: "memory");
        __builtin_amdgcn_s_barrier();
        __builtin_amdgcn_sched_barrier(0);
        unsigned short* dstm = pair ? j_s : i_s;
#pragma unroll
        for (int it = 0; it < 4; ++it) {
          int g = it * 256 + t;
          int cl = g >> 4, ch = g & 15;
          int s = (cl >> 2) & 7;
          bf8_t v = *(const bf8_t*)&gt[cl * 128 + ((ch ^ (s << 1)) * 8)];
          *(bf8_t*)(dstm + ((size_t)(h * 64 + cl) * NN + ii) * NN + k0 + ch * 8) = v;
        }
      }
    } else {
      int h = k - 8;
#pragma unroll
      for (int mt = 0; mt < 2; ++mt)
#pragma unroll
        for (int ct = 0; ct < 4; ++ct) acc3[mt][ct] = z4;
#pragma unroll
      for (int ct = 0; ct < 4; ++ct)
#pragma unroll
        for (int kk = 0; kk < 4; ++kk) {
          int rv = ct * 16 + lr;
          int slot = (kk * 4 + lh) ^ (rv & 7);
          bf8_t w = *(const bf8_t*)&buf[rv * 128 + slot * 8];
#pragma unroll
          for (int mt = 0; mt < 2; ++mt) acc3[mt][ct] = MFMA16(xf[mt][kk], w, acc3[mt][ct]);
        }
#pragma unroll
      for (int mt = 0; mt < 2; ++mt)
#pragma unroll
        for (int ct = 0; ct < 4; ++ct)
#pragma unroll
          for (int r = 0; r < 4; ++r) {
            int cl = ct * 16 + lr;
            int pos = wave * 32 + mt * 16 + lh * 4 + r;
            float gv = sigm(acc3[mt][ct][r] + bl[512 + h * 64 + cl]);
            int s2 = (pos >> 2) & 3;
            gt[pos * 64 + (cl ^ (s2 << 4))] = f2bf(gv);
          }
      asm volatile("s_waitcnt lgkmcnt(0)" ::: "memory");
      __builtin_amdgcn_s_barrier();
      __builtin_amdgcn_sched_barrier(0);
#pragma unroll
      for (int it = 0; it < 4; ++it) {
        int g = it * 256 + t;
        int p2 = g >> 3, cc2 = g & 7;
        int s2 = (p2 >> 2) & 3;
        bf8_t v = *(const bf8_t*)&gt[p2 * 64 + ((cc2 ^ (s2 << 1)) * 8)];
        *(bf8_t*)(g3 + (size_t)(ii * NN + k0 + p2) * CC + h * 64 + cc2 * 8) = v;
      }
    }
    __builtin_amdgcn_sched_barrier(0);
    __builtin_amdgcn_s_barrier();
    if (k + 2 <= 9) ISSUE(k + 2, k & 1);
  }
}

// ---------------- kB: per-channel GEMM out_pre[c][i][j] = sum_k i_s[c][i][k]*j_s[c][j][k]
// block: one channel, 128x128 tile; 4 waves in 2x2, each 64x64.
__global__ __launch_bounds__(256) void kB(const unsigned short* __restrict__ i_s,
                                          const unsigned short* __restrict__ j_s,
                                          float* __restrict__ out_pre) {
  __shared__ unsigned short At[128][32];
  __shared__ unsigned short Bt[128][32];
  int b = blockIdx.x;
  int logical = (b & 7) * 144 + (b >> 3);  // XCD-bijective swizzle (1152 = 8*144)
  int c = logical / 9;
  int tt = logical % 9;
  int i0 = (tt / 3) * 128, j0 = (tt % 3) * 128;
  const unsigned short* Ab = i_s + ((size_t)c * NN + i0) * NN;
  const unsigned short* Bb = j_s + ((size_t)c * NN + j0) * NN;
  int t = threadIdx.x, lane = t & 63, wave = t >> 6;
  int wi = (wave >> 1) * 64, wj = (wave & 1) * 64;
  int lr = lane & 15, lh = lane >> 4;
  int rsub = lane >> 2;        // 0..15 row within 16-row chunk
  int ksub = (lane & 3) * 8;   // element offset within BK=32

  f32x4_t z4 = {0.f, 0.f, 0.f, 0.f};
  f32x4_t acc[4][4];
#pragma unroll
  for (int mt = 0; mt < 4; ++mt)
#pragma unroll
    for (int nt = 0; nt < 4; ++nt) acc[mt][nt] = z4;

  for (int k0 = 0; k0 < NN; k0 += 32) {
#pragma unroll
    for (int half = 0; half < 2; ++half) {
      int r = half * 64 + wave * 16;  // wave-uniform base row
      __builtin_amdgcn_global_load_lds(
          (const __attribute__((address_space(1))) unsigned int*)(Ab + (size_t)(r + rsub) * NN + k0 + ksub),
          (__attribute__((address_space(3))) unsigned int*)&At[r][0], 16, 0, 0);
      __builtin_amdgcn_global_load_lds(
          (const __attribute__((address_space(1))) unsigned int*)(Bb + (size_t)(r + rsub) * NN + k0 + ksub),
          (__attribute__((address_space(3))) unsigned int*)&Bt[r][0], 16, 0, 0);
    }
    __syncthreads();
    bf8_t af2[4], bf2[4];
#pragma unroll
    for (int mt = 0; mt < 4; ++mt) af2[mt] = *(const bf8_t*)&At[wi + mt * 16 + lr][lh * 8];
#pragma unroll
    for (int nt = 0; nt < 4; ++nt) bf2[nt] = *(const bf8_t*)&Bt[wj + nt * 16 + lr][lh * 8];
#pragma unroll
    for (int mt = 0; mt < 4; ++mt)
#pragma unroll
      for (int nt = 0; nt < 4; ++nt) acc[mt][nt] = MFMA16(af2[mt], bf2[nt], acc[mt][nt]);
    __syncthreads();
  }
  float* orow = out_pre + ((size_t)c * NN + (i0 + wi)) * NN + (j0 + wj);
#pragma unroll
  for (int mt = 0; mt < 4; ++mt)
#pragma unroll
    for (int nt = 0; nt < 4; ++nt)
#pragma unroll
      for (int r = 0; r < 4; ++r)
        orow[(size_t)(mt * 16 + lh * 4 + r) * NN + nt * 16 + lr] = acc[mt][nt][r];
}

// ---------------- kC: LN2 + w2 + gate -> out [p][c] fp32 -----------------
// block: 128 positions (row ii, j0..j0+127), 256 threads.
__global__ __launch_bounds__(256) void kC(const float* __restrict__ out_pre,
                                          const float* __restrict__ n2g,
                                          const float* __restrict__ n2b,
                                          const unsigned short* __restrict__ w2bf,
                                          const float* __restrict__ b2,
                                          const unsigned short* __restrict__ g3,
                                          float* __restrict__ out) {
  __shared__ unsigned short xs2[128][136];
  int b = blockIdx.x;
  int ii = b / 3, j0 = (b % 3) * 128;
  int t = threadIdx.x, lane = t & 63, wave = t >> 6;
  {  // LN2: 2 threads per position, 64 channels each (held in registers)
    int pos = t >> 1, half = t & 1;
    const float* src = out_pre + (size_t)half * 64 * NPOS + (size_t)ii * NN + j0 + pos;
    float v[64];
    float s = 0.f;
#pragma unroll
    for (int a2 = 0; a2 < 64; ++a2) { v[a2] = src[(size_t)a2 * NPOS]; s += v[a2]; }
    s += __shfl_xor(s, 1);
    float mu = s * (1.0f / CC);
    float vs = 0.f;
#pragma unroll
    for (int a2 = 0; a2 < 64; ++a2) { float d = v[a2] - mu; vs += d * d; }
    vs += __shfl_xor(vs, 1);
    float rs = rsqrtf(vs * (1.0f / CC) + 1e-5f);
#pragma unroll
    for (int a8 = 0; a8 < 8; ++a8) {
      union { bf8_t v8; unsigned short e[8]; } u;
#pragma unroll
      for (int e2 = 0; e2 < 8; ++e2) {
        int c = half * 64 + a8 * 8 + e2;
        u.e[e2] = f2bf((v[a8 * 8 + e2] - mu) * rs * n2g[c] + n2b[c]);
      }
      *(bf8_t*)&xs2[pos][half * 64 + a8 * 8] = u.v8;
    }
  }
  __syncthreads();
  int lr = lane & 15, lh = lane >> 4;
  bf8_t af2[2][4];
#pragma unroll
  for (int mt = 0; mt < 2; ++mt)
#pragma unroll
    for (int kk = 0; kk < 4; ++kk)
      af2[mt][kk] = *(const bf8_t*)&xs2[wave * 32 + mt * 16 + lr][kk * 32 + lh * 8];
  f32x4_t z4 = {0.f, 0.f, 0.f, 0.f};
  f32x4_t acc[2][8];
#pragma unroll
  for (int mt = 0; mt < 2; ++mt)
#pragma unroll
    for (int nt = 0; nt < 8; ++nt) acc[mt][nt] = z4;
#pragma unroll
  for (int nt = 0; nt < 8; ++nt) {
#pragma unroll
    for (int kk = 0; kk < 4; ++kk) {
      bf8_t bw = *(const bf8_t*)(w2bf + (size_t)(nt * 16 + lr) * CC + kk * 32 + lh * 8);
#pragma unroll
      for (int mt = 0; mt < 2; ++mt) acc[mt][nt] = MFMA16(af2[mt][kk], bw, acc[mt][nt]);
    }
  }
#pragma unroll
  for (int mt = 0; mt < 2; ++mt)
#pragma unroll
    for (int nt = 0; nt < 8; ++nt)
#pragma unroll
      for (int r = 0; r < 4; ++r) {
        int posl = wave * 32 + mt * 16 + lh * 4 + r;
        int c = nt * 16 + lr;
        size_t p = (size_t)ii * NN + j0 + posl;
        float y = acc[mt][nt][r] + b2[c];
        out[p * CC + c] = y * bf2f(g3[p * CC + c]);
      }
}

extern "C" void kernel_launch(void* const* d_in, const int* in_sizes, int n_in,
                              void* d_out, int out_size, void* d_ws, size_t ws_size,
                              hipStream_t stream) {
  (void)in_sizes; (void)n_in; (void)out_size; (void)ws_size;
  const float* x2d  = (const float*)d_in[0];
  const float* n1g  = (const float*)d_in[1];
  const float* n1b  = (const float*)d_in[2];
  const float* n2g  = (const float*)d_in[3];
  const float* n2b  = (const float*)d_in[4];
  const float* w1i  = (const float*)d_in[5];
  const float* b1i  = (const float*)d_in[6];
  const float* w1j  = (const float*)d_in[7];
  const float* b1j  = (const float*)d_in[8];
  const float* w1is = (const float*)d_in[9];
  const float* b1is = (const float*)d_in[10];
  const float* w1js = (const float*)d_in[11];
  const float* b1js = (const float*)d_in[12];
  const float* w2   = (const float*)d_in[13];
  const float* b2   = (const float*)d_in[14];
  const float* w3   = (const float*)d_in[15];
  const float* b3   = (const float*)d_in[16];

  char* ws = (char*)d_ws;
  unsigned short* wcat = (unsigned short*)ws;            // 768*128*2 = 192 KiB (padded to 256 KiB)
  size_t TELEMS = (size_t)CC * NN * NN;                  // 18,874,368
  unsigned short* i_s = (unsigned short*)(ws + 262144);  // 36 MiB
  unsigned short* j_s = i_s + TELEMS;                    // 36 MiB
  unsigned short* g3  = j_s + TELEMS;                    // 36 MiB
  float* out_pre = (float*)(ws + 262144 + 3 * TELEMS * 2);  // 72 MiB
  float* outp = (float*)d_out;

  kW<<<96, 256, 0, stream>>>(w1i, w1is, w1j, w1js, w3, w2, wcat);
  kA<<<1152, 256, 0, stream>>>(x2d, n1g, n1b, wcat, b1i, b1is, b1j, b1js, b3, i_s, j_s, g3);
  kB<<<1152, 256, 0, stream>>>(i_s, j_s, out_pre);
  kC<<<1152, 256, 0, stream>>>(out_pre, n2g, n2b, wcat + 5 * CC * CC, b2, g3, outp);
}

// Round 4
// 178.047 us; speedup vs baseline: 1.2222x; 1.2222x over previous
//
#include <hip/hip_runtime.h>

#define NN 384
#define CC 128
#define NPOS (NN * NN)  // 147456

typedef short bf8_t __attribute__((ext_vector_type(8)));
typedef float f32x4_t __attribute__((ext_vector_type(4)));

#define MFMA16(a, b, c) __builtin_amdgcn_mfma_f32_16x16x32_bf16((a), (b), (c), 0, 0, 0)

__device__ __forceinline__ unsigned short f2bf(float f) {
  unsigned int u = __builtin_bit_cast(unsigned int, f);
  u += 0x7fffu + ((u >> 16) & 1u);  // RNE
  return (unsigned short)(u >> 16);
}
__device__ __forceinline__ float bf2f(unsigned short s) {
  return __builtin_bit_cast(float, ((unsigned int)s) << 16);
}
__device__ __forceinline__ float sigm(float x) { return 1.0f / (1.0f + __expf(-x)); }

// ---------------- kW: fp32 -> bf16 weight concat [768][128] -----------------
// rows 0-127: w1i, 128-255: w1i_s, 256-383: w1j, 384-511: w1j_s, 512-639: w3, 640-767: w2
__global__ __launch_bounds__(256) void kW(const float* __restrict__ a,
                                          const float* __restrict__ b,
                                          const float* __restrict__ c,
                                          const float* __restrict__ d,
                                          const float* __restrict__ e,
                                          const float* __restrict__ f,
                                          unsigned short* __restrict__ o) {
  int idx = (blockIdx.x * 256 + threadIdx.x) * 4;
  const float* s = f;  // compare-chain, not runtime-indexed array (avoids scratch)
  if (idx < 16384) s = a;
  else if (idx < 32768) s = b;
  else if (idx < 49152) s = c;
  else if (idx < 65536) s = d;
  else if (idx < 81920) s = e;
  int off = idx & 16383;
  float4 v = *(const float4*)(s + off);
  o[idx + 0] = f2bf(v.x);
  o[idx + 1] = f2bf(v.y);
  o[idx + 2] = f2bf(v.z);
  o[idx + 3] = f2bf(v.w);
}

// ---------------- kA: LN1 + 5 projections + gates, 10-phase dbuf pipeline ----
// block: 128 positions (row ii, k0..k0+127), 256 threads / 4 waves.
// LDS (50.5KB): wb dbuf 2x16KB (also LN staging), gather 16KB, bias table 2.5KB.
// launch_bounds(256,2): DO NOT cap tighter — (256,3) forced VGPR=84 and the
// accumulators spilled to scratch (+50MB fetch / +67MB write per dispatch, R3).
__global__ __launch_bounds__(256, 2) void kA(
    const float* __restrict__ x, const float* __restrict__ n1g,
    const float* __restrict__ n1b, const unsigned short* __restrict__ wcat,
    const float* __restrict__ b1i, const float* __restrict__ b1is,
    const float* __restrict__ b1j, const float* __restrict__ b1js,
    const float* __restrict__ b3v, unsigned short* __restrict__ i_s,
    unsigned short* __restrict__ j_s, unsigned short* __restrict__ g3) {
  __shared__ __align__(16) unsigned short lds[25856];
  // [0,8192): buf0   [8192,16384): buf1   (together = LN staging [128][128])
  // [16384,24576): gather tile    [24576,25856): bias table (640 floats)
  unsigned short* gt = lds + 16384;
  float* bl = (float*)(lds + 24576);

  int blk = blockIdx.x;
  int ii = blk / 3;
  int k0 = (blk % 3) * 128;
  int t = threadIdx.x;
  int lane = t & 63, wave = t >> 6;
  int lr = lane & 15, lh = lane >> 4;

  // ---- bias preload: rows m: 0=b1i 1=b1i_s 2=b1j 3=b1j_s 4=b3 ----
  if (t < 160) {
    int m = t >> 5, e4 = t & 31;
    const float* bp = (m == 0) ? b1i : (m == 1) ? b1is : (m == 2) ? b1j : (m == 3) ? b1js : b3v;
    ((float4*)bl)[m * 32 + e4] = ((const float4*)bp)[e4];
  }

  // ---- LN1: 2 threads per position, 64 channels each; XOR-swizzled LDS write --
  {
    int pos = t >> 1, half = t & 1;
    const float* xr = x + (size_t)(ii * NN + k0 + pos) * CC + half * 64;
    float v[64];
    float s = 0.f;
#pragma unroll
    for (int a = 0; a < 16; ++a) {
      float4 f4 = ((const float4*)xr)[a];
      v[4 * a + 0] = f4.x; v[4 * a + 1] = f4.y;
      v[4 * a + 2] = f4.z; v[4 * a + 3] = f4.w;
      s += f4.x + f4.y + f4.z + f4.w;
    }
    s += __shfl_xor(s, 1);
    float mu = s * (1.0f / CC);
    float vs = 0.f;
#pragma unroll
    for (int a = 0; a < 64; ++a) { float d = v[a] - mu; vs += d * d; }
    vs += __shfl_xor(vs, 1);
    float rs = rsqrtf(vs * (1.0f / CC) + 1e-5f);
#pragma unroll
    for (int a8 = 0; a8 < 8; ++a8) {
      union { bf8_t v8; unsigned short e[8]; } u;
#pragma unroll
      for (int e = 0; e < 8; ++e) {
        int c = half * 64 + a8 * 8 + e;
        u.e[e] = f2bf((v[a8 * 8 + e] - mu) * rs * n1g[c] + n1b[c]);
      }
      int slot = (half * 8 + a8) ^ (pos & 7);
      *(bf8_t*)&lds[pos * 128 + slot * 8] = u.v8;
    }
  }
  __syncthreads();

  // ---- X fragments for this wave's 32 positions (swizzled read) ----
  bf8_t xf[2][4];
#pragma unroll
  for (int nt = 0; nt < 2; ++nt)
#pragma unroll
    for (int kk = 0; kk < 4; ++kk) {
      int row = wave * 32 + nt * 16 + lr;
      int slot = (kk * 4 + lh) ^ (row & 7);
      xf[nt][kk] = *(const bf8_t*)&lds[row * 128 + slot * 8];
    }
  __syncthreads();

  // ---- 10-chunk pipeline. chunk k -> 64-row block blk64[k] of wcat ----
  // order: p0V h0, p0G h0, p0V h1, p0G h1, p1V h0, p1G h0, p1V h1, p1G h1, w3 h0, w3 h1
  constexpr int blk64[10] = {0, 2, 1, 3, 4, 6, 5, 7, 8, 9};
  auto ISSUE = [&](int k, int bsel) {
    const unsigned short* base = wcat + (size_t)blk64[k] * 8192;
#pragma unroll
    for (int it = 0; it < 4; ++it) {
      int u = it * 256 + t;
      int row = u >> 4, sl = u & 15;
      int slg = sl ^ (row & 7);  // pre-swizzled global source, linear LDS dest
      __builtin_amdgcn_global_load_lds(
          (const __attribute__((address_space(1))) unsigned int*)(base + row * CC + slg * 8),
          (__attribute__((address_space(3))) unsigned int*)(lds + bsel * 8192 + u * 8), 16, 0, 0);
    }
  };
  auto COMP = [&](f32x4_t (&A)[4][2], const unsigned short* buf) {
#pragma unroll
    for (int ct = 0; ct < 4; ++ct)
#pragma unroll
      for (int kk = 0; kk < 4; ++kk) {
        int rv = ct * 16 + lr;
        int slot = (kk * 4 + lh) ^ (rv & 7);
        bf8_t w = *(const bf8_t*)&buf[rv * 128 + slot * 8];
#pragma unroll
        for (int nt = 0; nt < 2; ++nt) A[ct][nt] = MFMA16(w, xf[nt][kk], A[ct][nt]);
      }
  };

  f32x4_t z4 = {0.f, 0.f, 0.f, 0.f};
  f32x4_t accV[4][2], accG[4][2], acc3[2][4];
  ISSUE(0, 0);
#pragma unroll 10
  for (int k = 0; k < 10; ++k) {
    // Counted waits (vmcnt retires in order): phases after a store-epilogue
    // phase leave those 4 stores in flight -> vmcnt(4); otherwise nothing is
    // newer than the chunk we need -> vmcnt(0).
    if (k == 2 || k == 4 || k == 6 || k == 8 || k == 9)
      asm volatile("s_waitcnt vmcnt(4)" ::: "memory");
    else
      asm volatile("s_waitcnt vmcnt(0)" ::: "memory");
    __builtin_amdgcn_s_barrier();
    __builtin_amdgcn_sched_barrier(0);
    // Prefetch next chunk into the buffer everyone just finished reading
    // (safe: all waves are past the barrier, i.e. past phase k-1's MFMA reads).
    if (k < 9) ISSUE(k + 1, (k + 1) & 1);
    const unsigned short* buf = lds + (k & 1) * 8192;
    if (k < 8) {
      if ((k & 1) == 0) {
#pragma unroll
        for (int ct = 0; ct < 4; ++ct)
#pragma unroll
          for (int nt = 0; nt < 2; ++nt) accV[ct][nt] = z4;
        COMP(accV, buf);
      } else {
#pragma unroll
        for (int ct = 0; ct < 4; ++ct)
#pragma unroll
          for (int nt = 0; nt < 2; ++nt) accG[ct][nt] = z4;
        COMP(accG, buf);
        // epilogue: gate + gather + cooperative 256B-contiguous stores
        int pair = k >> 2, h = (k >> 1) & 1;
#pragma unroll
        for (int ct = 0; ct < 4; ++ct)
#pragma unroll
          for (int nt = 0; nt < 2; ++nt)
#pragma unroll
            for (int r = 0; r < 4; ++r) {
              int cl = ct * 16 + lh * 4 + r;
              int c = h * 64 + cl;
              float val = accV[ct][nt][r] + bl[pair * 256 + c];
              float gat = accG[ct][nt][r] + bl[pair * 256 + 128 + c];
              int pos = wave * 32 + nt * 16 + lr;
              int sw = ((ct * 4 + lh) & 7) << 4;
              gt[cl * 128 + (pos ^ sw)] = f2bf(val * sigm(gat));
            }
        asm volatile("s_waitcnt lgkmcnt(0)" ::: "memory");
        __builtin_amdgcn_s_barrier();
        __builtin_amdgcn_sched_barrier(0);
        unsigned short* dstm = pair ? j_s : i_s;
#pragma unroll
        for (int it = 0; it < 4; ++it) {
          int g = it * 256 + t;
          int cl = g >> 4, ch = g & 15;
          int s = (cl >> 2) & 7;
          bf8_t v = *(const bf8_t*)&gt[cl * 128 + ((ch ^ (s << 1)) * 8)];
          *(bf8_t*)(dstm + ((size_t)(h * 64 + cl) * NN + ii) * NN + k0 + ch * 8) = v;
        }
      }
    } else {
      int h = k - 8;
#pragma unroll
      for (int mt = 0; mt < 2; ++mt)
#pragma unroll
        for (int ct = 0; ct < 4; ++ct) acc3[mt][ct] = z4;
#pragma unroll
      for (int ct = 0; ct < 4; ++ct)
#pragma unroll
        for (int kk = 0; kk < 4; ++kk) {
          int rv = ct * 16 + lr;
          int slot = (kk * 4 + lh) ^ (rv & 7);
          bf8_t w = *(const bf8_t*)&buf[rv * 128 + slot * 8];
#pragma unroll
          for (int mt = 0; mt < 2; ++mt) acc3[mt][ct] = MFMA16(xf[mt][kk], w, acc3[mt][ct]);
        }
#pragma unroll
      for (int mt = 0; mt < 2; ++mt)
#pragma unroll
        for (int ct = 0; ct < 4; ++ct)
#pragma unroll
          for (int r = 0; r < 4; ++r) {
            int cl = ct * 16 + lr;
            int pos = wave * 32 + mt * 16 + lh * 4 + r;
            float gv = sigm(acc3[mt][ct][r] + bl[512 + h * 64 + cl]);
            int s2 = (pos >> 2) & 3;
            gt[pos * 64 + (cl ^ (s2 << 4))] = f2bf(gv);
          }
      asm volatile("s_waitcnt lgkmcnt(0)" ::: "memory");
      __builtin_amdgcn_s_barrier();
      __builtin_amdgcn_sched_barrier(0);
#pragma unroll
      for (int it = 0; it < 4; ++it) {
        int g = it * 256 + t;
        int p2 = g >> 3, cc2 = g & 7;
        int s2 = (p2 >> 2) & 3;
        bf8_t v = *(const bf8_t*)&gt[p2 * 64 + ((cc2 ^ (s2 << 1)) * 8)];
        *(bf8_t*)(g3 + (size_t)(ii * NN + k0 + p2) * CC + h * 64 + cc2 * 8) = v;
      }
    }
  }
}

// ---------------- kB: per-channel GEMM out_pre[c][i][j] = sum_k i_s[c][i][k]*j_s[c][j][k]
// block: one channel, 128x128 tile; 4 waves in 2x2, each 64x64.
__global__ __launch_bounds__(256) void kB(const unsigned short* __restrict__ i_s,
                                          const unsigned short* __restrict__ j_s,
                                          float* __restrict__ out_pre) {
  __shared__ unsigned short At[128][32];
  __shared__ unsigned short Bt[128][32];
  int b = blockIdx.x;
  int logical = (b & 7) * 144 + (b >> 3);  // XCD-bijective swizzle (1152 = 8*144)
  int c = logical / 9;
  int tt = logical % 9;
  int i0 = (tt / 3) * 128, j0 = (tt % 3) * 128;
  const unsigned short* Ab = i_s + ((size_t)c * NN + i0) * NN;
  const unsigned short* Bb = j_s + ((size_t)c * NN + j0) * NN;
  int t = threadIdx.x, lane = t & 63, wave = t >> 6;
  int wi = (wave >> 1) * 64, wj = (wave & 1) * 64;
  int lr = lane & 15, lh = lane >> 4;
  int rsub = lane >> 2;        // 0..15 row within 16-row chunk
  int ksub = (lane & 3) * 8;   // element offset within BK=32

  f32x4_t z4 = {0.f, 0.f, 0.f, 0.f};
  f32x4_t acc[4][4];
#pragma unroll
  for (int mt = 0; mt < 4; ++mt)
#pragma unroll
    for (int nt = 0; nt < 4; ++nt) acc[mt][nt] = z4;

  for (int k0 = 0; k0 < NN; k0 += 32) {
#pragma unroll
    for (int half = 0; half < 2; ++half) {
      int r = half * 64 + wave * 16;  // wave-uniform base row
      __builtin_amdgcn_global_load_lds(
          (const __attribute__((address_space(1))) unsigned int*)(Ab + (size_t)(r + rsub) * NN + k0 + ksub),
          (__attribute__((address_space(3))) unsigned int*)&At[r][0], 16, 0, 0);
      __builtin_amdgcn_global_load_lds(
          (const __attribute__((address_space(1))) unsigned int*)(Bb + (size_t)(r + rsub) * NN + k0 + ksub),
          (__attribute__((address_space(3))) unsigned int*)&Bt[r][0], 16, 0, 0);
    }
    __syncthreads();
    bf8_t af2[4], bf2[4];
#pragma unroll
    for (int mt = 0; mt < 4; ++mt) af2[mt] = *(const bf8_t*)&At[wi + mt * 16 + lr][lh * 8];
#pragma unroll
    for (int nt = 0; nt < 4; ++nt) bf2[nt] = *(const bf8_t*)&Bt[wj + nt * 16 + lr][lh * 8];
#pragma unroll
    for (int mt = 0; mt < 4; ++mt)
#pragma unroll
      for (int nt = 0; nt < 4; ++nt) acc[mt][nt] = MFMA16(af2[mt], bf2[nt], acc[mt][nt]);
    __syncthreads();
  }
  float* orow = out_pre + ((size_t)c * NN + (i0 + wi)) * NN + (j0 + wj);
#pragma unroll
  for (int mt = 0; mt < 4; ++mt)
#pragma unroll
    for (int nt = 0; nt < 4; ++nt)
#pragma unroll
      for (int r = 0; r < 4; ++r)
        orow[(size_t)(mt * 16 + lh * 4 + r) * NN + nt * 16 + lr] = acc[mt][nt][r];
}

// ---------------- kC: LN2 + w2 + gate -> out [p][c] fp32 -----------------
// block: 128 positions (row ii, j0..j0+127), 256 threads.
__global__ __launch_bounds__(256) void kC(const float* __restrict__ out_pre,
                                          const float* __restrict__ n2g,
                                          const float* __restrict__ n2b,
                                          const unsigned short* __restrict__ w2bf,
                                          const float* __restrict__ b2,
                                          const unsigned short* __restrict__ g3,
                                          float* __restrict__ out) {
  __shared__ unsigned short xs2[128][136];
  int b = blockIdx.x;
  int ii = b / 3, j0 = (b % 3) * 128;
  int t = threadIdx.x, lane = t & 63, wave = t >> 6;
  {  // LN2: 2 threads per position, 64 channels each (held in registers)
    int pos = t >> 1, half = t & 1;
    const float* src = out_pre + (size_t)half * 64 * NPOS + (size_t)ii * NN + j0 + pos;
    float v[64];
    float s = 0.f;
#pragma unroll
    for (int a2 = 0; a2 < 64; ++a2) { v[a2] = src[(size_t)a2 * NPOS]; s += v[a2]; }
    s += __shfl_xor(s, 1);
    float mu = s * (1.0f / CC);
    float vs = 0.f;
#pragma unroll
    for (int a2 = 0; a2 < 64; ++a2) { float d = v[a2] - mu; vs += d * d; }
    vs += __shfl_xor(vs, 1);
    float rs = rsqrtf(vs * (1.0f / CC) + 1e-5f);
#pragma unroll
    for (int a8 = 0; a8 < 8; ++a8) {
      union { bf8_t v8; unsigned short e[8]; } u;
#pragma unroll
      for (int e2 = 0; e2 < 8; ++e2) {
        int c = half * 64 + a8 * 8 + e2;
        u.e[e2] = f2bf((v[a8 * 8 + e2] - mu) * rs * n2g[c] + n2b[c]);
      }
      *(bf8_t*)&xs2[pos][half * 64 + a8 * 8] = u.v8;
    }
  }
  __syncthreads();
  int lr = lane & 15, lh = lane >> 4;
  bf8_t af2[2][4];
#pragma unroll
  for (int mt = 0; mt < 2; ++mt)
#pragma unroll
    for (int kk = 0; kk < 4; ++kk)
      af2[mt][kk] = *(const bf8_t*)&xs2[wave * 32 + mt * 16 + lr][kk * 32 + lh * 8];
  f32x4_t z4 = {0.f, 0.f, 0.f, 0.f};
  f32x4_t acc[2][8];
#pragma unroll
  for (int mt = 0; mt < 2; ++mt)
#pragma unroll
    for (int nt = 0; nt < 8; ++nt) acc[mt][nt] = z4;
#pragma unroll
  for (int nt = 0; nt < 8; ++nt) {
#pragma unroll
    for (int kk = 0; kk < 4; ++kk) {
      bf8_t bw = *(const bf8_t*)(w2bf + (size_t)(nt * 16 + lr) * CC + kk * 32 + lh * 8);
#pragma unroll
      for (int mt = 0; mt < 2; ++mt) acc[mt][nt] = MFMA16(af2[mt][kk], bw, acc[mt][nt]);
    }
  }
#pragma unroll
  for (int mt = 0; mt < 2; ++mt)
#pragma unroll
    for (int nt = 0; nt < 8; ++nt)
#pragma unroll
      for (int r = 0; r < 4; ++r) {
        int posl = wave * 32 + mt * 16 + lh * 4 + r;
        int c = nt * 16 + lr;
        size_t p = (size_t)ii * NN + j0 + posl;
        float y = acc[mt][nt][r] + b2[c];
        out[p * CC + c] = y * bf2f(g3[p * CC + c]);
      }
}

extern "C" void kernel_launch(void* const* d_in, const int* in_sizes, int n_in,
                              void* d_out, int out_size, void* d_ws, size_t ws_size,
                              hipStream_t stream) {
  (void)in_sizes; (void)n_in; (void)out_size; (void)ws_size;
  const float* x2d  = (const float*)d_in[0];
  const float* n1g  = (const float*)d_in[1];
  const float* n1b  = (const float*)d_in[2];
  const float* n2g  = (const float*)d_in[3];
  const float* n2b  = (const float*)d_in[4];
  const float* w1i  = (const float*)d_in[5];
  const float* b1i  = (const float*)d_in[6];
  const float* w1j  = (const float*)d_in[7];
  const float* b1j  = (const float*)d_in[8];
  const float* w1is = (const float*)d_in[9];
  const float* b1is = (const float*)d_in[10];
  const float* w1js = (const float*)d_in[11];
  const float* b1js = (const float*)d_in[12];
  const float* w2   = (const float*)d_in[13];
  const float* b2   = (const float*)d_in[14];
  const float* w3   = (const float*)d_in[15];
  const float* b3   = (const float*)d_in[16];

  char* ws = (char*)d_ws;
  unsigned short* wcat = (unsigned short*)ws;            // 768*128*2 = 192 KiB (padded to 256 KiB)
  size_t TELEMS = (size_t)CC * NN * NN;                  // 18,874,368
  unsigned short* i_s = (unsigned short*)(ws + 262144);  // 36 MiB
  unsigned short* j_s = i_s + TELEMS;                    // 36 MiB
  unsigned short* g3  = j_s + TELEMS;                    // 36 MiB
  float* out_pre = (float*)(ws + 262144 + 3 * TELEMS * 2);  // 72 MiB
  float* outp = (float*)d_out;

  kW<<<96, 256, 0, stream>>>(w1i, w1is, w1j, w1js, w3, w2, wcat);
  kA<<<1152, 256, 0, stream>>>(x2d, n1g, n1b, wcat, b1i, b1is, b1j, b1js, b3, i_s, j_s, g3);
  kB<<<1152, 256, 0, stream>>>(i_s, j_s, out_pre);
  kC<<<1152, 256, 0, stream>>>(out_pre, n2g, n2b, wcat + 5 * CC * CC, b2, g3, outp);
}